// Round 11
// baseline (1026.038 us; speedup 1.0000x reference)
//
#include <hip/hip_runtime.h>
#include <hip/hip_bf16.h>
#include <math.h>

#define BB 8
#define NCLS 21
#define NANCH 2048
#define TOPK_N 100

// ---------------- workspace layout (bytes) ----------------
// Activations in C8HW8 tiling [b][C/8][Hp][Wp][8], 1-px halo, bf16 hi/lo.
static const size_t OFF_X1HI = 0;           // 8*8*130*258*8*2 = 34,344,960
static const size_t OFF_X1LO = 34344960;    // -> 68,689,920
static const size_t OFF_X2HI = 68689920;    // 8*16*66*130*8*2 = 17,571,840 -> 86,261,760
static const size_t OFF_X2LO = 86261760;    // -> 103,833,600
static const size_t OFF_FTHI = 103833600;   // 8*32*34*66*8*2 = 9,191,424 -> 113,025,024
static const size_t OFF_FTLO = 113025024;   // -> 122,216,448
static const size_t ZERO_BYTES = 122216448; // everything above gets zeroed (halos!)
// weights (packed once per launch)
static const size_t OFF_WT1  = 122216448;   // 27*64*4 = 6,912 (fp32, conv1 direct)
static const size_t OFF_A2H  = 122223616;   // 128*576*2 = 147,456
static const size_t OFF_A2L  = 122371072;   // 147,456
static const size_t OFF_A3H  = 122518528;   // 256*1152*2 = 589,824
static const size_t OFF_A3L  = 123108352;   // 589,824
static const size_t OFF_AHH  = 123698176;   // 64*2304*2 = 294,912
static const size_t OFF_AHL  = 123993088;   // 294,912
static const size_t OFF_AP1H = 124288000;   // 256*2304*2 = 1,179,648
static const size_t OFF_AP1L = 125467648;   // 1,179,648
static const size_t OFF_WTP2 = 126647296;   // 256*32*4 = 32,768
static const size_t OFF_BH   = 126680064;   // 64*4 (pad to 126,680,576)
// tensors
static const size_t OFF_HOUT = 126680576;   // 8*64*2048*4 = 4,194,304 -> 130,874,880
static const size_t OFF_P1   = 130874880;   // 8*256*2048*4 = 16,777,216 -> 147,652,096
static const size_t OFF_PROTO= 147652096;   // 2,097,152 -> 149,749,248
static const size_t OFF_BOXES= 149749248;   // 262,144 -> 150,011,392
static const size_t OFF_SCORES=150011392;   // 65,536 -> 150,076,928
static const size_t OFF_LABELS=150076928;   // 65,536 -> 150,142,464
static const size_t OFF_ORDER= 150142464;   // 65,536 -> 150,208,000
static const size_t OFF_SB   = 150208000;   // 262,144 -> 150,470,144
static const size_t OFF_IOU  = 150470144;   // 4,194,304 -> 154,664,448
static const size_t OFF_KEEP = 154664448;   // 3,200 (pad)
static const size_t OFF_MAXB = 154668032;   // 32 (pad to 154,668,544)
static const size_t OFF_M    = 154668544;   // 8*100*2048*4 = 6,553,600 -> 161,222,144

// ---------------- output layout (float elements) ----------------
static const size_t OUT_BOXES  = 0;
static const size_t OUT_SCORES = 3200;
static const size_t OUT_LABELS = 4000;
static const size_t OUT_MASKS  = 4800;
static const size_t OUT_VALID  = 104862400;

typedef __attribute__((ext_vector_type(8))) short bf16x8;
typedef __attribute__((ext_vector_type(4))) float f32x4;

__device__ __forceinline__ unsigned encf(float f){
  unsigned u = __float_as_uint(f);
  return (u & 0x80000000u) ? ~u : (u | 0x80000000u);
}
__device__ __forceinline__ float decf(unsigned u){
  unsigned b = (u & 0x80000000u) ? (u & 0x7fffffffu) : ~u;
  return __uint_as_float(b);
}
__device__ __forceinline__ short f2bf(float f){
  __hip_bfloat16 h = __float2bfloat16(f);
  return *(short*)&h;
}
__device__ __forceinline__ float bf2f(short h){
  return __uint_as_float(((unsigned)(unsigned short)h) << 16);
}

// zero activation planes + maxb init (first 8 threads)
__global__ void zerok(float4* __restrict__ p, long n4, unsigned* __restrict__ maxb){
  long i = (long)blockIdx.x*256 + threadIdx.x;
  if (i < BB) maxb[i] = 0u;
  if (i < n4) p[i] = make_float4(0.f,0.f,0.f,0.f);
}

// ---------------- weight packers ----------------
// fp32 pre-transpose for conv1: [co][ci][9] -> [ci*9+k][co]
template<int CIN,int COUT,int KK>
__global__ void packw(const float* __restrict__ w, float* __restrict__ wT){
  int i = blockIdx.x*256 + threadIdx.x;
  if (i >= CIN*KK*COUT) return;
  int co = i % COUT; int r = i / COUT;
  int ci = r / KK,  k = r % KK;
  wT[i] = w[(co*CIN + ci)*KK + k];
}

// bf16 split pack into MFMA-FRAGMENT ORDER:
// A[mt][ks][lane][8]: lane's 8 shorts = A[mt*16 + (lane&15)][ks*32 + (lane>>4)*8 .. +8]
// where logical k = tap*CIN + ci (tap-major, matching cgemm's tap loop).
template<int CIN,int COUT>
__global__ void packA(const float* __restrict__ w, short* __restrict__ Ahi,
                      short* __restrict__ Alo){
  constexpr int K = CIN*9;
  constexpr int KS = K/32;
  int i = blockIdx.x*256 + threadIdx.x;
  if (i >= COUT*K) return;
  int sub  = i & 7;
  int lane = (i >> 3) & 63;
  int rest = i >> 9;
  int ks = rest % KS;
  int mt = rest / KS;
  int m = mt*16 + (lane & 15);
  int k = ks*32 + (lane >> 4)*8 + sub;
  int tap = k / CIN, ci = k - tap*CIN;
  float v = w[(m*CIN + ci)*9 + tap];
  short h = f2bf(v);
  Ahi[i] = h;
  Alo[i] = f2bf(v - bf2f(h));
}

// heads pack: 21 cls | 4 box | 32 coef | 7 zero -> fragment-order A[64][2304] hi/lo + bias
__global__ void packAh(const float* __restrict__ cw, const float* __restrict__ bw,
                       const float* __restrict__ kw, const float* __restrict__ cb,
                       const float* __restrict__ bb, const float* __restrict__ kb,
                       short* __restrict__ Ahi, short* __restrict__ Alo,
                       float* __restrict__ bh){
  int i = blockIdx.x*256 + threadIdx.x;
  if (i < 64){
    float v = 0.f;
    if (i < 21) v = cb[i]; else if (i < 25) v = bb[i-21]; else if (i < 57) v = kb[i-25];
    bh[i] = v;
  }
  if (i >= 64*2304) return;
  constexpr int KS = 72;               // 2304/32
  int sub  = i & 7;
  int lane = (i >> 3) & 63;
  int rest = i >> 9;
  int ks = rest % KS;
  int mt = rest / KS;
  int m = mt*16 + (lane & 15);
  int k = ks*32 + (lane >> 4)*8 + sub;
  int tap = k >> 8, ci = k & 255;
  float v = 0.f;
  if (m < 21)      v = cw[(m*256 + ci)*9 + tap];
  else if (m < 25) v = bw[((m-21)*256 + ci)*9 + tap];
  else if (m < 57) v = kw[((m-25)*256 + ci)*9 + tap];
  short h = f2bf(v);
  Ahi[i] = h;
  Alo[i] = f2bf(v - bf2f(h));
}

// ---------------- conv1: direct fp32, epilogue -> C8HW8 padded bf16 hi/lo ----------------
__global__ __launch_bounds__(256) void conv1k(const float* __restrict__ img,
    const float* __restrict__ wT, const float* __restrict__ bias,
    short* __restrict__ x1hi, short* __restrict__ x1lo){
  const int b   = blockIdx.z;
  const int co0 = blockIdx.y * 16;
  const int g   = blockIdx.x*256 + threadIdx.x;   // 16384 = 128 rows * 128 groups
  const int y  = g >> 7;
  const int x0 = (g & 127) << 1;                  // 2 outputs/thread

  float acc[16][2];
#pragma unroll
  for (int c=0;c<16;c++){
    float bv = bias[co0+c];
    acc[c][0] = bv; acc[c][1] = bv;
  }
  int   off[3][5];
  float msk[3][5];
#pragma unroll
  for (int kh=0;kh<3;kh++){
    int iy = y*2 - 1 + kh;
    bool okr = (iy >= 0) && (iy < 256);
    int ro = okr ? iy*512 : 0;
#pragma unroll
    for (int t=0;t<5;t++){
      int col = x0*2 - 1 + t;
      bool ok = okr && (col >= 0) && (col < 512);
      off[kh][t] = ok ? (ro + col) : 0;
      msk[kh][t] = ok ? 1.f : 0.f;
    }
  }
  const float* inb = img + (size_t)b*3*256*512;
  for (int ci=0; ci<3; ci++){
    const float* inc = inb + (size_t)ci*256*512;
    float v[3][5];
#pragma unroll
    for (int kh=0;kh<3;kh++)
#pragma unroll
      for (int t=0;t<5;t++)
        v[kh][t] = inc[off[kh][t]] * msk[kh][t];
    const float* wp = wT + ci*9*64 + co0;
#pragma unroll
    for (int kh=0;kh<3;kh++)
#pragma unroll
    for (int kw=0;kw<3;kw++){
      const float* wq = wp + (kh*3+kw)*64;        // wave-uniform
#pragma unroll
      for (int c=0;c<16;c++){
        float wv = wq[c];
        acc[c][0] = fmaf(wv, v[kh][2*0+kw], acc[c][0]);
        acc[c][1] = fmaf(wv, v[kh][2*1+kw], acc[c][1]);
      }
    }
  }
#pragma unroll
  for (int s=0;s<2;s++){
    short hv[16] __attribute__((aligned(16)));
    short lv[16] __attribute__((aligned(16)));
#pragma unroll
    for (int c=0;c<16;c++){
      float r = fmaxf(acc[c][s], 0.f);
      short h = f2bf(r);
      hv[c] = h;
      lv[c] = f2bf(r - bf2f(h));
    }
#pragma unroll
    for (int g2=0; g2<2; g2++){
      size_t ad = (((size_t)(b*8 + (co0>>3) + g2)*130 + (y+1))*258 + (x0+s+1))*8;
      *(bf16x8*)(x1hi + ad) = *(bf16x8*)(hv + g2*8);
      *(bf16x8*)(x1lo + ad) = *(bf16x8*)(lv + g2*8);
    }
  }
}

// ---------------- implicit-GEMM conv via MFMA, C8HW8 activations (R9 config) ----------------
template<int CIN,int K,int M,int MW,int NW,int OW,int OHh,int S,int IPH,int IPW,
         bool SPLIT,int EMODE,int OPH,int OPW>
__global__ __launch_bounds__(NW*64) void cgemm(
    const short* __restrict__ Ahi, const short* __restrict__ Alo,
    const short* __restrict__ Bhi, const short* __restrict__ Blo,
    const float* __restrict__ bias, float* __restrict__ outf,
    short* __restrict__ outhi, short* __restrict__ outlo){
  static_assert(CIN % 32 == 0, "CIN must be multiple of 32");
  constexpr int NT = OW*OHh;
  constexpr int KS = K/32;
  constexpr int CG = CIN/8;
  const int b    = blockIdx.z;
  const int wave = threadIdx.x >> 6;
  const int lane = threadIdx.x & 63;
  const int lm = lane & 15, lq = lane >> 4;
  const int m0 = (blockIdx.y * NW + wave) * (MW*16);
  const int n0 = blockIdx.x * 64;

  int oy[4], ox[4];
#pragma unroll
  for (int j=0;j<4;j++){
    int n = n0 + j*16 + lm;
    oy[j] = n / OW; ox[j] = n % OW;
  }

  f32x4 acc[MW][4];
#pragma unroll
  for (int i=0;i<MW;i++)
#pragma unroll
    for (int j=0;j<4;j++) acc[i][j] = (f32x4){0.f,0.f,0.f,0.f};

  const short* Ah_l = Ahi + (size_t)lane*8;
  const short* Al_l = Alo + (size_t)lane*8;
  const int mt0 = m0 >> 4;

  const size_t plane = (size_t)IPH*IPW;
  const short* Bh0 = Bhi + ((size_t)b*CG + lq)*plane*8;
  const short* Bl0 = Blo + ((size_t)b*CG + lq)*plane*8;

#pragma unroll 3
  for (int tap=0; tap<9; tap++){
    const int dy = tap/3, dx = tap%3;
    size_t pix[4];
#pragma unroll
    for (int j=0;j<4;j++)
      pix[j] = (size_t)(oy[j]*S + dy)*IPW + (size_t)(ox[j]*S + dx);
    const int ksb = tap*(CIN/32);
#pragma unroll
    for (int kc=0; kc<CIN; kc+=32){
      const int ks = ksb + (kc>>5);
      const size_t koff = (size_t)(kc>>3)*plane;
      bf16x8 ah[MW], bh_[4];
#pragma unroll
      for (int i=0;i<MW;i++)
        ah[i] = *(const bf16x8*)(Ah_l + ((size_t)(mt0+i)*KS + ks)*512);
#pragma unroll
      for (int j=0;j<4;j++) bh_[j] = *(const bf16x8*)(Bh0 + (koff + pix[j])*8);
      if constexpr (SPLIT){
        bf16x8 al[MW], bl_[4];
#pragma unroll
        for (int i=0;i<MW;i++)
          al[i] = *(const bf16x8*)(Al_l + ((size_t)(mt0+i)*KS + ks)*512);
#pragma unroll
        for (int j=0;j<4;j++) bl_[j] = *(const bf16x8*)(Bl0 + (koff + pix[j])*8);
#pragma unroll
        for (int j=0;j<4;j++)
#pragma unroll
          for (int i=0;i<MW;i++)
            acc[i][j] = __builtin_amdgcn_mfma_f32_16x16x32_bf16(ah[i], bh_[j], acc[i][j], 0,0,0);
#pragma unroll
        for (int j=0;j<4;j++)
#pragma unroll
          for (int i=0;i<MW;i++)
            acc[i][j] = __builtin_amdgcn_mfma_f32_16x16x32_bf16(ah[i], bl_[j], acc[i][j], 0,0,0);
#pragma unroll
        for (int j=0;j<4;j++)
#pragma unroll
          for (int i=0;i<MW;i++)
            acc[i][j] = __builtin_amdgcn_mfma_f32_16x16x32_bf16(al[i], bh_[j], acc[i][j], 0,0,0);
      } else {
#pragma unroll
        for (int j=0;j<4;j++)
#pragma unroll
          for (int i=0;i<MW;i++)
            acc[i][j] = __builtin_amdgcn_mfma_f32_16x16x32_bf16(ah[i], bh_[j], acc[i][j], 0,0,0);
      }
    }
  }

#pragma unroll
  for (int i=0;i<MW;i++){
#pragma unroll
    for (int r=0;r<4;r++){
      const int m = m0 + i*16 + lq*4 + r;
      const float bv = bias[m];
      if constexpr (EMODE == 0){
#pragma unroll
        for (int j=0;j<4;j++){
          float v = fmaxf(acc[i][j][r] + bv, 0.f);
          short h = f2bf(v);
          short l = f2bf(v - bf2f(h));
          size_t ad = ((((size_t)(b*(M/8) + (m>>3))*OPH + (oy[j]+1))*OPW + (ox[j]+1)))*8 + (m&7);
          outhi[ad] = h;
          outlo[ad] = l;
        }
      } else {
        float* cp = outf + ((size_t)b*M + m)*NT + n0 + lm;
#pragma unroll
        for (int j=0;j<4;j++){
          float v = acc[i][j][r] + bv;
          if constexpr (EMODE == 2) v = fmaxf(v, 0.f);
          cp[j*16] = v;
        }
      }
    }
  }
}

// ---------------- 1x1 conv 256->32 (fp32, mask path) ----------------
__global__ __launch_bounds__(256) void pw2k2(const float* __restrict__ p1,
    const float* __restrict__ wT, const float* __restrict__ bias,
    float* __restrict__ proto){
  const int b  = blockIdx.y;
  const int sp = blockIdx.x*256 + threadIdx.x;
  float acc[32];
#pragma unroll
  for (int c=0;c<32;c++) acc[c] = bias[c];
  const float* pb = p1 + (size_t)b*256*NANCH + sp;
  for (int ci=0;ci<256;ci++){
    float v = pb[(size_t)ci*NANCH];
    const float* wq = wT + ci*32;
#pragma unroll
    for (int c=0;c<32;c++) acc[c] = fmaf(v, wq[c], acc[c]);
  }
#pragma unroll
  for (int c=0;c<32;c++)
    proto[((size_t)b*32 + c)*NANCH + sp] = acc[c];
}

// ---------------- decode: softmax/labels/boxes + per-batch max(boxes) ----------------
__global__ void decodek(const float* __restrict__ hout,
                        float* __restrict__ boxes, float* __restrict__ scores,
                        int* __restrict__ labels, unsigned* __restrict__ maxb){
  const int b = blockIdx.y;
  const int n = blockIdx.x*blockDim.x + threadIdx.x;
  const float* cp = hout + (size_t)b*64*NANCH + n;
  float l[NCLS];
  float M = -1e30f;
#pragma unroll
  for (int c=0;c<NCLS;c++){ l[c] = cp[(size_t)c*NANCH]; M = fmaxf(M, l[c]); }
  float denom = 0.f;
#pragma unroll
  for (int c=0;c<NCLS;c++) denom += expf(l[c]-M);
  float best = -1.f; int bi = 0;
#pragma unroll
  for (int c=0;c<NCLS-1;c++){
    float e = expf(l[c]-M);
    if (e > best){ best = e; bi = c; }
  }
  scores[(size_t)b*NANCH + n] = best/denom;
  labels[(size_t)b*NANCH + n] = bi;

  float dx = cp[21*(size_t)NANCH], dy = cp[22*(size_t)NANCH];
  float dw = cp[23*(size_t)NANCH], dh = cp[24*(size_t)NANCH];
  const int yy = n >> 6, xx = n & 63;
  float cx = (xx+0.5f)*8.f, cy = (yy+0.5f)*8.f;
  float px = cx + dx*32.f, py = cy + dy*32.f;
  float pw = 32.f*expf(dw), ph = 32.f*expf(dh);
  float x1 = px - 0.5f*pw, y1 = py - 0.5f*ph;
  float x2 = px + 0.5f*pw, y2 = py + 0.5f*ph;
  float* bo = boxes + ((size_t)b*NANCH + n)*4;
  bo[0]=x1; bo[1]=y1; bo[2]=x2; bo[3]=y2;
  float mx = fmaxf(fmaxf(x1,y1), fmaxf(x2,y2));
#pragma unroll
  for (int off=32; off>0; off>>=1) mx = fmaxf(mx, __shfl_down(mx, off));
  if ((threadIdx.x & 63) == 0) atomicMax(maxb + b, encf(mx));
}

// ---------------- rank-based stable descending argsort (replaces bitonic sortk) ----------------
// rank_i = #{j: s_j>s_i} + #{j<i: s_j==s_i}  ==  stable argsort(-scores).
// 64 blocks (8 n-chunks x 8 batches), scores in LDS (broadcast reads).
__global__ __launch_bounds__(256) void ranksort(const float* __restrict__ scores,
    const float* __restrict__ boxes, const int* __restrict__ labels,
    const unsigned* __restrict__ maxb, int* __restrict__ order,
    float* __restrict__ sb){
  __shared__ float sc[NANCH];
  const int b = blockIdx.y;
  const int i = blockIdx.x*256 + threadIdx.x;     // 0..2047
  for (int t = threadIdx.x; t < NANCH; t += 256)
    sc[t] = scores[(size_t)b*NANCH + t];
  __syncthreads();
  const float si = sc[i];
  int rank = 0;
#pragma unroll 8
  for (int j=0;j<NANCH;j++){
    float sj = sc[j];
    rank += (int)((sj > si) | ((sj == si) & (j < i)));
  }
  order[(size_t)b*NANCH + rank] = i;
  float mboff = decf(maxb[b]) + 1.0f;
  float off = (float)labels[(size_t)b*NANCH + i] * mboff;
  const float* bo = boxes + ((size_t)b*NANCH + i)*4;
  float* sp = sb + ((size_t)b*NANCH + rank)*4;
  sp[0]=bo[0]+off; sp[1]=bo[1]+off; sp[2]=bo[2]+off; sp[3]=bo[3]+off;
}

// ---------------- IoU>thr bitmask ----------------
__global__ void ioumask(const float* __restrict__ sb, unsigned long long* __restrict__ iou){
  const int b = blockIdx.y;
  const int gid = blockIdx.x*blockDim.x + threadIdx.x;
  const int i = gid >> 5, w = gid & 31;
  const float* base = sb + (size_t)b*NANCH*4;
  unsigned long long bits = 0ull;
  const int j0 = w << 6;
  if (j0 + 63 > i){
    float x1=base[i*4], y1=base[i*4+1], x2=base[i*4+2], y2=base[i*4+3];
    float ai = (x2-x1)*(y2-y1);
    for (int jj=0;jj<64;jj++){
      int j = j0 + jj;
      if (j > i){
        float bx1=base[j*4], by1=base[j*4+1], bx2=base[j*4+2], by2=base[j*4+3];
        float lx=fmaxf(x1,bx1), ly=fmaxf(y1,by1);
        float rx=fminf(x2,bx2), ry=fminf(y2,by2);
        float ww=fmaxf(rx-lx,0.f), hh=fmaxf(ry-ly,0.f);
        float inter = ww*hh;
        float aj = (bx2-bx1)*(by2-by1);
        float v = inter/(ai + aj - inter + 1e-9f);
        if (v > 0.5f) bits |= (1ull << jj);
      }
    }
  }
  iou[((size_t)b*NANCH + i)*32 + w] = bits;
}

// ---------------- greedy NMS scan ----------------
__global__ void nmsscan(const unsigned long long* __restrict__ iou,
                        const int* __restrict__ order, int* __restrict__ keep){
  const int b = blockIdx.x, lane = threadIdx.x;
  unsigned long long sup = 0ull;
  int k = 0;
  for (int i=0; i<NANCH && k<TOPK_N; i++){
    int wi = i >> 6, bi = i & 63;
    unsigned long long wv = __shfl(sup, wi);
    if (!((wv >> bi) & 1ull)){
      if (lane == 0) keep[b*TOPK_N + k] = order[(size_t)b*NANCH + i];
      k++;
      unsigned long long row = (lane < 32) ? iou[((size_t)b*NANCH + i)*32 + lane] : 0ull;
      sup |= row;
    }
  }
  for (int r = lane; r < TOPK_N; r += 64)
    if (r >= k) keep[b*TOPK_N + r] = -1;
}

// ---------------- gather kept results ----------------
__global__ void gatherk(const int* __restrict__ keep, const float* __restrict__ boxes,
                        const float* __restrict__ scores, const int* __restrict__ labels,
                        float* __restrict__ out){
  const int b = blockIdx.x, r = threadIdx.x;
  if (r >= TOPK_N) return;
  int ki = keep[b*TOPK_N + r];
  float valid = (ki >= 0) ? 1.f : 0.f;
  int kc = (ki < 0) ? 0 : ki;
  const float* bo = boxes + ((size_t)b*NANCH + kc)*4;
#pragma unroll
  for (int c=0;c<4;c++) out[OUT_BOXES + ((size_t)b*TOPK_N + r)*4 + c] = bo[c]*valid;
  out[OUT_SCORES + b*TOPK_N + r] = scores[(size_t)b*NANCH + kc]*valid;
  out[OUT_LABELS + b*TOPK_N + r] = (ki >= 0) ? (float)labels[(size_t)b*NANCH + kc] : 0.f;
  out[OUT_VALID  + b*TOPK_N + r] = valid;
}

// ---------------- mask logits + sigmoid (R5-proven) ----------------
__global__ void maskm(const int* __restrict__ keep, const float* __restrict__ hout,
                      const float* __restrict__ proto, float* __restrict__ m){
  const int b = blockIdx.z, r = blockIdx.y;
  const int s = blockIdx.x*blockDim.x + threadIdx.x;
  __shared__ float cf[32];
  int ki = keep[b*TOPK_N + r];
  int kc = (ki < 0) ? 0 : ki;
  if (threadIdx.x < 32)
    cf[threadIdx.x] = hout[((size_t)b*64 + 25 + threadIdx.x)*NANCH + kc];
  __syncthreads();
  float acc = 0.f;
#pragma unroll
  for (int p=0;p<32;p++) acc = fmaf(cf[p], proto[((size_t)b*32 + p)*NANCH + s], acc);
  m[((size_t)b*TOPK_N + r)*NANCH + s] = 1.f/(1.f + expf(-acc));
}

// ---------------- bilinear 32x64 -> 256x512, threshold (R5-proven) ----------------
__global__ void resizek(const float* __restrict__ m, const int* __restrict__ keep,
                        float* __restrict__ out){
  const int b = blockIdx.z, r = blockIdx.y;
  const int pid = blockIdx.x*blockDim.x + threadIdx.x;
  const int y  = pid >> 7;
  const int x4 = (pid & 127) << 2;
  bool valid = keep[b*TOPK_N + r] >= 0;
  const float* mb = m + ((size_t)b*TOPK_N + r)*NANCH;
  float sy = (y + 0.5f)*0.125f - 0.5f;
  sy = fminf(fmaxf(sy, 0.f), 31.f);
  int y0 = (int)floorf(sy);
  int y1 = min(y0+1, 31);
  float wy = sy - (float)y0;
  const float* r0 = mb + y0*64;
  const float* r1 = mb + y1*64;
  float res[4];
#pragma unroll
  for (int k=0;k<4;k++){
    int x = x4 + k;
    float sx = (x + 0.5f)*0.125f - 0.5f;
    sx = fminf(fmaxf(sx, 0.f), 63.f);
    int x0 = (int)floorf(sx);
    int x1 = min(x0+1, 63);
    float wx = sx - (float)x0;
    float t0 = r0[x0]*(1.f-wy) + r1[x0]*wy;
    float t1 = r0[x1]*(1.f-wy) + r1[x1]*wy;
    float v  = t0*(1.f-wx) + t1*wx;
    res[k] = (v > 0.5f && valid) ? 1.f : 0.f;
  }
  float4 v4 = make_float4(res[0], res[1], res[2], res[3]);
  *(float4*)(out + OUT_MASKS + (((size_t)b*TOPK_N + r)*256 + y)*512 + x4) = v4;
}

extern "C" void kernel_launch(void* const* d_in, const int* in_sizes, int n_in,
                              void* d_out, int out_size, void* d_ws, size_t ws_size,
                              hipStream_t stream) {
  const float* images=(const float*)d_in[0];
  const float* w1=(const float*)d_in[1];  const float* b1=(const float*)d_in[2];
  const float* w2=(const float*)d_in[3];  const float* b2=(const float*)d_in[4];
  const float* w3=(const float*)d_in[5];  const float* b3=(const float*)d_in[6];
  const float* pw1=(const float*)d_in[7]; const float* pb1=(const float*)d_in[8];
  const float* pw2=(const float*)d_in[9]; const float* pb2=(const float*)d_in[10];
  const float* cw=(const float*)d_in[11]; const float* cb=(const float*)d_in[12];
  const float* bw=(const float*)d_in[13]; const float* bb=(const float*)d_in[14];
  const float* kw=(const float*)d_in[15]; const float* kb=(const float*)d_in[16];
  float* out = (float*)d_out;
  char* ws = (char*)d_ws;

  short* x1hi = (short*)(ws + OFF_X1HI);
  short* x1lo = (short*)(ws + OFF_X1LO);
  short* x2hi = (short*)(ws + OFF_X2HI);
  short* x2lo = (short*)(ws + OFF_X2LO);
  short* fthi = (short*)(ws + OFF_FTHI);
  short* ftlo = (short*)(ws + OFF_FTLO);
  float* wT1  = (float*)(ws + OFF_WT1);
  short* a2h  = (short*)(ws + OFF_A2H);
  short* a2l  = (short*)(ws + OFF_A2L);
  short* a3h  = (short*)(ws + OFF_A3H);
  short* a3l  = (short*)(ws + OFF_A3L);
  short* ahh  = (short*)(ws + OFF_AHH);
  short* ahl  = (short*)(ws + OFF_AHL);
  short* ap1h = (short*)(ws + OFF_AP1H);
  short* ap1l = (short*)(ws + OFF_AP1L);
  float* wTp2 = (float*)(ws + OFF_WTP2);
  float* bh   = (float*)(ws + OFF_BH);
  float* hout = (float*)(ws + OFF_HOUT);
  float* p1   = (float*)(ws + OFF_P1);
  float* proto= (float*)(ws + OFF_PROTO);
  float* boxes= (float*)(ws + OFF_BOXES);
  float* scores=(float*)(ws + OFF_SCORES);
  int*   labels=(int*)  (ws + OFF_LABELS);
  int*   order =(int*)  (ws + OFF_ORDER);
  float* sb   = (float*)(ws + OFF_SB);
  unsigned long long* iou = (unsigned long long*)(ws + OFF_IOU);
  int*   keep = (int*)  (ws + OFF_KEEP);
  unsigned* maxb = (unsigned*)(ws + OFF_MAXB);
  float* m    = (float*)(ws + OFF_M);

  // zero activation planes + maxb (halos must be 0; harness poisons ws with 0xAA)
  zerok<<<dim3((unsigned)(ZERO_BYTES/16/256)), 256, 0, stream>>>((float4*)ws, (long)(ZERO_BYTES/16), maxb);

  // weight packing
  packw<3,64,9>  <<<dim3(7),    256, 0, stream>>>(w1, wT1);
  packA<64,128>  <<<dim3(288),  256, 0, stream>>>(w2, a2h, a2l);
  packA<128,256> <<<dim3(1152), 256, 0, stream>>>(w3, a3h, a3l);
  packA<256,256> <<<dim3(2304), 256, 0, stream>>>(pw1, ap1h, ap1l);
  packAh<<<dim3(576), 256, 0, stream>>>(cw, bw, kw, cb, bb, kb, ahh, ahl, bh);
  packw<256,32,1><<<dim3(32),   256, 0, stream>>>(pw2, wTp2);

  // conv1: direct fp32 -> x1 C8HW8 padded hi/lo
  conv1k<<<dim3(64,4,BB), 256, 0, stream>>>(images, wT1, b1, x1hi, x1lo);

  // conv2: split-bf16 implicit GEMM (R9 config: MW=2, NW=4)
  cgemm<64,576,128,2,4,128,64,2,130,258,true,0,66,130>
      <<<dim3(128,1,BB), 256, 0, stream>>>(a2h, a2l, x1hi, x1lo, b2, nullptr, x2hi, x2lo);

  // conv3: split-bf16 implicit GEMM (R9 config)
  cgemm<128,1152,256,2,4,64,32,2,66,130,true,0,34,66>
      <<<dim3(32,2,BB), 256, 0, stream>>>(a3h, a3l, x2hi, x2lo, b3, nullptr, fthi, ftlo);

  // heads: split-bf16 implicit GEMM, feat -> hout fp32 (R9 config)
  cgemm<256,2304,64,2,2,64,32,1,34,66,true,1,1,1>
      <<<dim3(32,1,BB), 128, 0, stream>>>(ahh, ahl, fthi, ftlo, bh, hout, nullptr, nullptr);

  // pw1 (mask path): plain bf16 implicit GEMM + relu (R9 config)
  cgemm<256,2304,256,2,4,64,32,1,34,66,false,2,1,1>
      <<<dim3(32,2,BB), 256, 0, stream>>>(ap1h, ap1l, fthi, fthi, pb1, p1, nullptr, nullptr);

  pw2k2<<<dim3(8,BB), 256, 0, stream>>>(p1, wTp2, pb2, proto);

  // decode + NMS
  decodek<<<dim3(8,BB), 256, 0, stream>>>(hout, boxes, scores, labels, maxb);
  ranksort<<<dim3(8,BB), 256, 0, stream>>>(scores, boxes, labels, maxb, order, sb);
  ioumask<<<dim3(256,BB), 256, 0, stream>>>(sb, iou);
  nmsscan<<<dim3(BB), 64, 0, stream>>>(iou, order, keep);
  gatherk<<<dim3(BB), 128, 0, stream>>>(keep, boxes, scores, labels, out);

  // masks (R5-proven pair: maskm -> resizek)
  maskm<<<dim3(8,TOPK_N,BB), 256, 0, stream>>>(keep, hout, proto, m);
  resizek<<<dim3(128,TOPK_N,BB), 256, 0, stream>>>(m, keep, out);
}

// Round 13
// 1006.001 us; speedup vs baseline: 1.0199x; 1.0199x over previous
//
#include <hip/hip_runtime.h>
#include <hip/hip_bf16.h>
#include <math.h>

#define BB 8
#define NCLS 21
#define NANCH 2048
#define TOPK_N 100

// ---------------- workspace layout (bytes) ----------------
// Activations in C8HW8 tiling [b][C/8][Hp][Wp][8], 1-px halo, bf16 hi/lo.
static const size_t OFF_X1HI = 0;           // 8*8*130*258*8*2 = 34,344,960
static const size_t OFF_X1LO = 34344960;    // -> 68,689,920
static const size_t OFF_X2HI = 68689920;    // 8*16*66*130*8*2 = 17,571,840 -> 86,261,760
static const size_t OFF_X2LO = 86261760;    // -> 103,833,600
static const size_t OFF_FTHI = 103833600;   // 8*32*34*66*8*2 = 9,191,424 -> 113,025,024
static const size_t OFF_FTLO = 113025024;   // -> 122,216,448
static const size_t ZERO_BYTES = 122216448; // everything above gets zeroed (halos!)
// weights (packed once per launch)
static const size_t OFF_WT1  = 122216448;   // 27*64*4 = 6,912 (fp32, conv1 direct)
static const size_t OFF_A2H  = 122223616;   // 128*576*2 = 147,456
static const size_t OFF_A2L  = 122371072;   // 147,456
static const size_t OFF_A3H  = 122518528;   // 256*1152*2 = 589,824
static const size_t OFF_A3L  = 123108352;   // 589,824
static const size_t OFF_AHH  = 123698176;   // 64*2304*2 = 294,912
static const size_t OFF_AHL  = 123993088;   // 294,912
static const size_t OFF_AP1H = 124288000;   // 256*2304*2 = 1,179,648
static const size_t OFF_AP1L = 125467648;   // 1,179,648
static const size_t OFF_WTP2 = 126647296;   // 256*32*4 = 32,768
static const size_t OFF_BH   = 126680064;   // 64*4 (pad to 126,680,576)
// tensors
static const size_t OFF_HOUT = 126680576;   // 8*64*2048*4 = 4,194,304 -> 130,874,880
static const size_t OFF_P1   = 130874880;   // 8*256*2048*4 = 16,777,216 -> 147,652,096
static const size_t OFF_PROTO= 147652096;   // 2,097,152 -> 149,749,248
static const size_t OFF_BOXES= 149749248;   // 262,144 -> 150,011,392
static const size_t OFF_SCORES=150011392;   // 65,536 -> 150,076,928
static const size_t OFF_LABELS=150076928;   // 65,536 -> 150,142,464
static const size_t OFF_ORDER= 150142464;   // 65,536 -> 150,208,000
static const size_t OFF_SB   = 150208000;   // 262,144 -> 150,470,144
static const size_t OFF_IOU  = 150470144;   // 4,194,304 -> 154,664,448
static const size_t OFF_KEEP = 154664448;   // 3,200 (pad)
static const size_t OFF_MAXB = 154668032;   // 32 (pad to 154,668,544)
static const size_t OFF_M    = 154668544;   // 8*100*2048*4 = 6,553,600 -> 161,222,144

// ---------------- output layout (float elements) ----------------
static const size_t OUT_BOXES  = 0;
static const size_t OUT_SCORES = 3200;
static const size_t OUT_LABELS = 4000;
static const size_t OUT_MASKS  = 4800;
static const size_t OUT_VALID  = 104862400;

typedef __attribute__((ext_vector_type(8))) short bf16x8;
typedef __attribute__((ext_vector_type(4))) float f32x4;

__device__ __forceinline__ unsigned encf(float f){
  unsigned u = __float_as_uint(f);
  return (u & 0x80000000u) ? ~u : (u | 0x80000000u);
}
__device__ __forceinline__ float decf(unsigned u){
  unsigned b = (u & 0x80000000u) ? (u & 0x7fffffffu) : ~u;
  return __uint_as_float(b);
}
__device__ __forceinline__ short f2bf(float f){
  __hip_bfloat16 h = __float2bfloat16(f);
  return *(short*)&h;
}
__device__ __forceinline__ float bf2f(short h){
  return __uint_as_float(((unsigned)(unsigned short)h) << 16);
}

// zero activation planes + maxb init (first 8 threads)
__global__ void zerok(float4* __restrict__ p, long n4, unsigned* __restrict__ maxb){
  long i = (long)blockIdx.x*256 + threadIdx.x;
  if (i < BB) maxb[i] = 0u;
  if (i < n4) p[i] = make_float4(0.f,0.f,0.f,0.f);
}

// ---------------- weight packers ----------------
template<int CIN,int COUT,int KK>
__global__ void packw(const float* __restrict__ w, float* __restrict__ wT){
  int i = blockIdx.x*256 + threadIdx.x;
  if (i >= CIN*KK*COUT) return;
  int co = i % COUT; int r = i / COUT;
  int ci = r / KK,  k = r % KK;
  wT[i] = w[(co*CIN + ci)*KK + k];
}

// bf16 split pack into MFMA-FRAGMENT ORDER (k = tap*CIN + ci, tap-major)
template<int CIN,int COUT>
__global__ void packA(const float* __restrict__ w, short* __restrict__ Ahi,
                      short* __restrict__ Alo){
  constexpr int K = CIN*9;
  constexpr int KS = K/32;
  int i = blockIdx.x*256 + threadIdx.x;
  if (i >= COUT*K) return;
  int sub  = i & 7;
  int lane = (i >> 3) & 63;
  int rest = i >> 9;
  int ks = rest % KS;
  int mt = rest / KS;
  int m = mt*16 + (lane & 15);
  int k = ks*32 + (lane >> 4)*8 + sub;
  int tap = k / CIN, ci = k - tap*CIN;
  float v = w[(m*CIN + ci)*9 + tap];
  short h = f2bf(v);
  Ahi[i] = h;
  Alo[i] = f2bf(v - bf2f(h));
}

__global__ void packAh(const float* __restrict__ cw, const float* __restrict__ bw,
                       const float* __restrict__ kw, const float* __restrict__ cb,
                       const float* __restrict__ bb, const float* __restrict__ kb,
                       short* __restrict__ Ahi, short* __restrict__ Alo,
                       float* __restrict__ bh){
  int i = blockIdx.x*256 + threadIdx.x;
  if (i < 64){
    float v = 0.f;
    if (i < 21) v = cb[i]; else if (i < 25) v = bb[i-21]; else if (i < 57) v = kb[i-25];
    bh[i] = v;
  }
  if (i >= 64*2304) return;
  constexpr int KS = 72;               // 2304/32
  int sub  = i & 7;
  int lane = (i >> 3) & 63;
  int rest = i >> 9;
  int ks = rest % KS;
  int mt = rest / KS;
  int m = mt*16 + (lane & 15);
  int k = ks*32 + (lane >> 4)*8 + sub;
  int tap = k >> 8, ci = k & 255;
  float v = 0.f;
  if (m < 21)      v = cw[(m*256 + ci)*9 + tap];
  else if (m < 25) v = bw[((m-21)*256 + ci)*9 + tap];
  else if (m < 57) v = kw[((m-25)*256 + ci)*9 + tap];
  short h = f2bf(v);
  Ahi[i] = h;
  Alo[i] = f2bf(v - bf2f(h));
}

// ---------------- conv1: direct fp32, epilogue -> C8HW8 padded bf16 hi/lo ----------------
__global__ __launch_bounds__(256) void conv1k(const float* __restrict__ img,
    const float* __restrict__ wT, const float* __restrict__ bias,
    short* __restrict__ x1hi, short* __restrict__ x1lo){
  const int b   = blockIdx.z;
  const int co0 = blockIdx.y * 16;
  const int g   = blockIdx.x*256 + threadIdx.x;
  const int y  = g >> 7;
  const int x0 = (g & 127) << 1;

  float acc[16][2];
#pragma unroll
  for (int c=0;c<16;c++){
    float bv = bias[co0+c];
    acc[c][0] = bv; acc[c][1] = bv;
  }
  int   off[3][5];
  float msk[3][5];
#pragma unroll
  for (int kh=0;kh<3;kh++){
    int iy = y*2 - 1 + kh;
    bool okr = (iy >= 0) && (iy < 256);
    int ro = okr ? iy*512 : 0;
#pragma unroll
    for (int t=0;t<5;t++){
      int col = x0*2 - 1 + t;
      bool ok = okr && (col >= 0) && (col < 512);
      off[kh][t] = ok ? (ro + col) : 0;
      msk[kh][t] = ok ? 1.f : 0.f;
    }
  }
  const float* inb = img + (size_t)b*3*256*512;
  for (int ci=0; ci<3; ci++){
    const float* inc = inb + (size_t)ci*256*512;
    float v[3][5];
#pragma unroll
    for (int kh=0;kh<3;kh++)
#pragma unroll
      for (int t=0;t<5;t++)
        v[kh][t] = inc[off[kh][t]] * msk[kh][t];
    const float* wp = wT + ci*9*64 + co0;
#pragma unroll
    for (int kh=0;kh<3;kh++)
#pragma unroll
    for (int kw=0;kw<3;kw++){
      const float* wq = wp + (kh*3+kw)*64;
#pragma unroll
      for (int c=0;c<16;c++){
        float wv = wq[c];
        acc[c][0] = fmaf(wv, v[kh][2*0+kw], acc[c][0]);
        acc[c][1] = fmaf(wv, v[kh][2*1+kw], acc[c][1]);
      }
    }
  }
#pragma unroll
  for (int s=0;s<2;s++){
    short hv[16] __attribute__((aligned(16)));
    short lv[16] __attribute__((aligned(16)));
#pragma unroll
    for (int c=0;c<16;c++){
      float r = fmaxf(acc[c][s], 0.f);
      short h = f2bf(r);
      hv[c] = h;
      lv[c] = f2bf(r - bf2f(h));
    }
#pragma unroll
    for (int g2=0; g2<2; g2++){
      size_t ad = (((size_t)(b*8 + (co0>>3) + g2)*130 + (y+1))*258 + (x0+s+1))*8;
      *(bf16x8*)(x1hi + ad) = *(bf16x8*)(hv + g2*8);
      *(bf16x8*)(x1lo + ad) = *(bf16x8*)(lv + g2*8);
    }
  }
}

// ---------------- cgemm (global-direct B) — conv2 (OW=128); R9-exact ----------------
template<int CIN,int K,int M,int MW,int NW,int OW,int OHh,int S,int IPH,int IPW,
         bool SPLIT,int EMODE,int OPH,int OPW>
__global__ __launch_bounds__(NW*64) void cgemm(
    const short* __restrict__ Ahi, const short* __restrict__ Alo,
    const short* __restrict__ Bhi, const short* __restrict__ Blo,
    const float* __restrict__ bias, float* __restrict__ outf,
    short* __restrict__ outhi, short* __restrict__ outlo){
  static_assert(CIN % 32 == 0, "CIN must be multiple of 32");
  constexpr int NT = OW*OHh;
  constexpr int KS = K/32;
  constexpr int CG = CIN/8;
  const int b    = blockIdx.z;
  const int wave = threadIdx.x >> 6;
  const int lane = threadIdx.x & 63;
  const int lm = lane & 15, lq = lane >> 4;
  const int m0 = (blockIdx.y * NW + wave) * (MW*16);
  const int n0 = blockIdx.x * 64;

  int oy[4], ox[4];
#pragma unroll
  for (int j=0;j<4;j++){
    int n = n0 + j*16 + lm;
    oy[j] = n / OW; ox[j] = n % OW;
  }

  f32x4 acc[MW][4];
#pragma unroll
  for (int i=0;i<MW;i++)
#pragma unroll
    for (int j=0;j<4;j++) acc[i][j] = (f32x4){0.f,0.f,0.f,0.f};

  const short* Ah_l = Ahi + (size_t)lane*8;
  const short* Al_l = Alo + (size_t)lane*8;
  const int mt0 = m0 >> 4;

  const size_t plane = (size_t)IPH*IPW;
  const short* Bh0 = Bhi + ((size_t)b*CG + lq)*plane*8;
  const short* Bl0 = Blo + ((size_t)b*CG + lq)*plane*8;

#pragma unroll 3
  for (int tap=0; tap<9; tap++){
    const int dy = tap/3, dx = tap%3;
    size_t pix[4];
#pragma unroll
    for (int j=0;j<4;j++)
      pix[j] = (size_t)(oy[j]*S + dy)*IPW + (size_t)(ox[j]*S + dx);
    const int ksb = tap*(CIN/32);
#pragma unroll
    for (int kc=0; kc<CIN; kc+=32){
      const int ks = ksb + (kc>>5);
      const size_t koff = (size_t)(kc>>3)*plane;
      bf16x8 ah[MW], bh_[4];
#pragma unroll
      for (int i=0;i<MW;i++)
        ah[i] = *(const bf16x8*)(Ah_l + ((size_t)(mt0+i)*KS + ks)*512);
#pragma unroll
      for (int j=0;j<4;j++) bh_[j] = *(const bf16x8*)(Bh0 + (koff + pix[j])*8);
      if constexpr (SPLIT){
        bf16x8 al[MW], bl_[4];
#pragma unroll
        for (int i=0;i<MW;i++)
          al[i] = *(const bf16x8*)(Al_l + ((size_t)(mt0+i)*KS + ks)*512);
#pragma unroll
        for (int j=0;j<4;j++) bl_[j] = *(const bf16x8*)(Bl0 + (koff + pix[j])*8);
#pragma unroll
        for (int j=0;j<4;j++)
#pragma unroll
          for (int i=0;i<MW;i++)
            acc[i][j] = __builtin_amdgcn_mfma_f32_16x16x32_bf16(ah[i], bh_[j], acc[i][j], 0,0,0);
#pragma unroll
        for (int j=0;j<4;j++)
#pragma unroll
          for (int i=0;i<MW;i++)
            acc[i][j] = __builtin_amdgcn_mfma_f32_16x16x32_bf16(ah[i], bl_[j], acc[i][j], 0,0,0);
#pragma unroll
        for (int j=0;j<4;j++)
#pragma unroll
          for (int i=0;i<MW;i++)
            acc[i][j] = __builtin_amdgcn_mfma_f32_16x16x32_bf16(al[i], bh_[j], acc[i][j], 0,0,0);
      } else {
#pragma unroll
        for (int j=0;j<4;j++)
#pragma unroll
          for (int i=0;i<MW;i++)
            acc[i][j] = __builtin_amdgcn_mfma_f32_16x16x32_bf16(ah[i], bh_[j], acc[i][j], 0,0,0);
      }
    }
  }

#pragma unroll
  for (int i=0;i<MW;i++){
#pragma unroll
    for (int r=0;r<4;r++){
      const int m = m0 + i*16 + lq*4 + r;
      const float bv = bias[m];
      if constexpr (EMODE == 0){
#pragma unroll
        for (int j=0;j<4;j++){
          float v = fmaxf(acc[i][j][r] + bv, 0.f);
          short h = f2bf(v);
          short l = f2bf(v - bf2f(h));
          size_t ad = ((((size_t)(b*(M/8) + (m>>3))*OPH + (oy[j]+1))*OPW + (ox[j]+1)))*8 + (m&7);
          outhi[ad] = h;
          outlo[ad] = l;
        }
      } else {
        float* cp = outf + ((size_t)b*M + m)*NT + n0 + lm;
#pragma unroll
        for (int j=0;j<4;j++){
          float v = acc[i][j][r] + bv;
          if constexpr (EMODE == 2) v = fmaxf(v, 0.f);
          cp[j*16] = v;
        }
      }
    }
  }
}

// ---------------- cgemm_row: LDS-staged HI B row, BIT-EXACT R9 order ----------------
// One output row per block (oy = blockIdx.x, OW=64). Per dy: stage the full-CIN
// padded hi input row into LDS ([g][p][8], dense loads), then run the EXACT R9
// k-sequence (tap = dy*3+dx ascending, kc inner; hh/hl/lh MFMA order unchanged).
// lo-B loads stay global-direct (R9-identical addresses) -> results bit-match R9.
template<int CIN,int K,int M,int MW,int NW,int S,int IPH,int IPW,
         bool SPLIT,int EMODE,int OPH,int OPW>
__global__ __launch_bounds__(NW*64) void cgemm_row(
    const short* __restrict__ Ahi, const short* __restrict__ Alo,
    const short* __restrict__ Bhi, const short* __restrict__ Blo,
    const float* __restrict__ bias, float* __restrict__ outf,
    short* __restrict__ outhi, short* __restrict__ outlo){
  static_assert(CIN % 32 == 0, "CIN must be multiple of 32");
  constexpr int NT = 64*32;
  constexpr int KS = K/32;
  constexpr int CG = CIN/8;
  __shared__ short sB[CG*IPW*8];       // hi row, layout [g][p][8]

  const int b    = blockIdx.z;
  const int oy   = blockIdx.x;
  const int wave = threadIdx.x >> 6;
  const int lane = threadIdx.x & 63;
  const int lm = lane & 15, lq = lane >> 4;
  const int m0 = (blockIdx.y * NW + wave) * (MW*16);
  const int tid = threadIdx.x;

  int ox[4];
#pragma unroll
  for (int j=0;j<4;j++) ox[j] = j*16 + lm;

  f32x4 acc[MW][4];
#pragma unroll
  for (int i=0;i<MW;i++)
#pragma unroll
    for (int j=0;j<4;j++) acc[i][j] = (f32x4){0.f,0.f,0.f,0.f};

  const short* Ah_l = Ahi + (size_t)lane*8;
  const short* Al_l = Alo + (size_t)lane*8;
  const int mt0 = m0 >> 4;
  const size_t plane = (size_t)IPH*IPW;
  const short* Bl0 = Blo + ((size_t)b*CG + lq)*plane*8;   // lo: global (R9 path)

#pragma unroll 1
  for (int dy=0; dy<3; dy++){
    const int iy = oy*S + dy;
    __syncthreads();                   // prior-iteration LDS reads complete
    {
      const short* srch = Bhi + ((size_t)b*CG*IPH + iy)*IPW*8;  // +g*plane*8 per group
      for (int c = tid; c < CG*IPW; c += NW*64){
        int g = c / IPW, p = c - g*IPW;
        *(bf16x8*)(&sB[(g*IPW + p)*8]) =
          *(const bf16x8*)(srch + ((size_t)g*plane + p)*8);
      }
    }
    __syncthreads();
#pragma unroll
    for (int dx=0; dx<3; dx++){
      const int tap = dy*3 + dx;
      const int ksb = tap*(CIN/32);
#pragma unroll
      for (int kc=0; kc<CIN; kc+=32){
        const int ks = ksb + (kc>>5);
        bf16x8 ah[MW], bh_[4];
#pragma unroll
        for (int i=0;i<MW;i++)
          ah[i] = *(const bf16x8*)(Ah_l + ((size_t)(mt0+i)*KS + ks)*512);
#pragma unroll
        for (int j=0;j<4;j++){
          int p = ox[j]*S + dx;
          bh_[j] = *(const bf16x8*)(&sB[(((kc>>3) + lq)*IPW + p)*8]);
        }
        if constexpr (SPLIT){
          const size_t koff = (size_t)(kc>>3)*plane;
          bf16x8 al[MW], bl_[4];
#pragma unroll
          for (int i=0;i<MW;i++)
            al[i] = *(const bf16x8*)(Al_l + ((size_t)(mt0+i)*KS + ks)*512);
#pragma unroll
          for (int j=0;j<4;j++){
            size_t pix = (size_t)iy*IPW + (size_t)(ox[j]*S + dx);
            bl_[j] = *(const bf16x8*)(Bl0 + (koff + pix)*8);
          }
#pragma unroll
          for (int j=0;j<4;j++)
#pragma unroll
            for (int i=0;i<MW;i++)
              acc[i][j] = __builtin_amdgcn_mfma_f32_16x16x32_bf16(ah[i], bh_[j], acc[i][j], 0,0,0);
#pragma unroll
          for (int j=0;j<4;j++)
#pragma unroll
            for (int i=0;i<MW;i++)
              acc[i][j] = __builtin_amdgcn_mfma_f32_16x16x32_bf16(ah[i], bl_[j], acc[i][j], 0,0,0);
#pragma unroll
          for (int j=0;j<4;j++)
#pragma unroll
            for (int i=0;i<MW;i++)
              acc[i][j] = __builtin_amdgcn_mfma_f32_16x16x32_bf16(al[i], bh_[j], acc[i][j], 0,0,0);
        } else {
#pragma unroll
          for (int j=0;j<4;j++)
#pragma unroll
            for (int i=0;i<MW;i++)
              acc[i][j] = __builtin_amdgcn_mfma_f32_16x16x32_bf16(ah[i], bh_[j], acc[i][j], 0,0,0);
        }
      }
    }
  }

#pragma unroll
  for (int i=0;i<MW;i++){
#pragma unroll
    for (int r=0;r<4;r++){
      const int m = m0 + i*16 + lq*4 + r;
      const float bv = bias[m];
      if constexpr (EMODE == 0){
#pragma unroll
        for (int j=0;j<4;j++){
          float v = fmaxf(acc[i][j][r] + bv, 0.f);
          short h = f2bf(v);
          short l = f2bf(v - bf2f(h));
          size_t ad = ((((size_t)(b*(M/8) + (m>>3))*OPH + (oy+1))*OPW + (ox[j]+1)))*8 + (m&7);
          outhi[ad] = h;
          outlo[ad] = l;
        }
      } else {
        float* cp = outf + ((size_t)b*M + m)*NT + oy*64 + lm;
#pragma unroll
        for (int j=0;j<4;j++){
          float v = acc[i][j][r] + bv;
          if constexpr (EMODE == 2) v = fmaxf(v, 0.f);
          cp[j*16] = v;
        }
      }
    }
  }
}

// ---------------- 1x1 conv 256->32 (fp32, mask path) ----------------
__global__ __launch_bounds__(256) void pw2k2(const float* __restrict__ p1,
    const float* __restrict__ wT, const float* __restrict__ bias,
    float* __restrict__ proto){
  const int b  = blockIdx.y;
  const int sp = blockIdx.x*256 + threadIdx.x;
  float acc[32];
#pragma unroll
  for (int c=0;c<32;c++) acc[c] = bias[c];
  const float* pb = p1 + (size_t)b*256*NANCH + sp;
  for (int ci=0;ci<256;ci++){
    float v = pb[(size_t)ci*NANCH];
    const float* wq = wT + ci*32;
#pragma unroll
    for (int c=0;c<32;c++) acc[c] = fmaf(v, wq[c], acc[c]);
  }
#pragma unroll
  for (int c=0;c<32;c++)
    proto[((size_t)b*32 + c)*NANCH + sp] = acc[c];
}

// ---------------- decode ----------------
__global__ void decodek(const float* __restrict__ hout,
                        float* __restrict__ boxes, float* __restrict__ scores,
                        int* __restrict__ labels, unsigned* __restrict__ maxb){
  const int b = blockIdx.y;
  const int n = blockIdx.x*blockDim.x + threadIdx.x;
  const float* cp = hout + (size_t)b*64*NANCH + n;
  float l[NCLS];
  float M = -1e30f;
#pragma unroll
  for (int c=0;c<NCLS;c++){ l[c] = cp[(size_t)c*NANCH]; M = fmaxf(M, l[c]); }
  float denom = 0.f;
#pragma unroll
  for (int c=0;c<NCLS;c++) denom += expf(l[c]-M);
  float best = -1.f; int bi = 0;
#pragma unroll
  for (int c=0;c<NCLS-1;c++){
    float e = expf(l[c]-M);
    if (e > best){ best = e; bi = c; }
  }
  scores[(size_t)b*NANCH + n] = best/denom;
  labels[(size_t)b*NANCH + n] = bi;

  float dx = cp[21*(size_t)NANCH], dy = cp[22*(size_t)NANCH];
  float dw = cp[23*(size_t)NANCH], dh = cp[24*(size_t)NANCH];
  const int yy = n >> 6, xx = n & 63;
  float cx = (xx+0.5f)*8.f, cy = (yy+0.5f)*8.f;
  float px = cx + dx*32.f, py = cy + dy*32.f;
  float pw = 32.f*expf(dw), ph = 32.f*expf(dh);
  float x1 = px - 0.5f*pw, y1 = py - 0.5f*ph;
  float x2 = px + 0.5f*pw, y2 = py + 0.5f*ph;
  float* bo = boxes + ((size_t)b*NANCH + n)*4;
  bo[0]=x1; bo[1]=y1; bo[2]=x2; bo[3]=y2;
  float mx = fmaxf(fmaxf(x1,y1), fmaxf(x2,y2));
#pragma unroll
  for (int off=32; off>0; off>>=1) mx = fmaxf(mx, __shfl_down(mx, off));
  if ((threadIdx.x & 63) == 0) atomicMax(maxb + b, encf(mx));
}

// ---------------- stable descending sort (bitonic, R9-proven) ----------------
__global__ void __launch_bounds__(1024) sortk(const float* __restrict__ scores,
                     const float* __restrict__ boxes, const int* __restrict__ labels,
                     const unsigned* __restrict__ maxb,
                     int* __restrict__ order, float* __restrict__ sb){
  __shared__ float sc[NANCH];
  __shared__ int   id[NANCH];
  const int b = blockIdx.x, t = threadIdx.x;
  for (int i=t;i<NANCH;i+=1024){ sc[i]=scores[(size_t)b*NANCH+i]; id[i]=i; }
  __syncthreads();
  for (int k=2;k<=NANCH;k<<=1){
    for (int j=k>>1;j>0;j>>=1){
      for (int i=t;i<NANCH;i+=1024){
        int ixj = i ^ j;
        if (ixj > i){
          float sa=sc[i], sb_=sc[ixj]; int ia=id[i], ib=id[ixj];
          bool dir = ((i & k) == 0);
          bool before_ba = (sb_ > sa) || (sb_ == sa && ib < ia);
          if (before_ba == dir){ sc[i]=sb_; sc[ixj]=sa; id[i]=ib; id[ixj]=ia; }
        }
      }
      __syncthreads();
    }
  }
  float mboff = decf(maxb[b]) + 1.0f;
  for (int r=t;r<NANCH;r+=1024){
    int o = id[r];
    order[(size_t)b*NANCH + r] = o;
    float off = (float)labels[(size_t)b*NANCH + o] * mboff;
    const float* bo = boxes + ((size_t)b*NANCH + o)*4;
    float* sp = sb + ((size_t)b*NANCH + r)*4;
    sp[0]=bo[0]+off; sp[1]=bo[1]+off; sp[2]=bo[2]+off; sp[3]=bo[3]+off;
  }
}

// ---------------- IoU>thr bitmask ----------------
__global__ void ioumask(const float* __restrict__ sb, unsigned long long* __restrict__ iou){
  const int b = blockIdx.y;
  const int gid = blockIdx.x*blockDim.x + threadIdx.x;
  const int i = gid >> 5, w = gid & 31;
  const float* base = sb + (size_t)b*NANCH*4;
  unsigned long long bits = 0ull;
  const int j0 = w << 6;
  if (j0 + 63 > i){
    float x1=base[i*4], y1=base[i*4+1], x2=base[i*4+2], y2=base[i*4+3];
    float ai = (x2-x1)*(y2-y1);
    for (int jj=0;jj<64;jj++){
      int j = j0 + jj;
      if (j > i){
        float bx1=base[j*4], by1=base[j*4+1], bx2=base[j*4+2], by2=base[j*4+3];
        float lx=fmaxf(x1,bx1), ly=fmaxf(y1,by1);
        float rx=fminf(x2,bx2), ry=fminf(y2,by2);
        float ww=fmaxf(rx-lx,0.f), hh=fmaxf(ry-ly,0.f);
        float inter = ww*hh;
        float aj = (bx2-bx1)*(by2-by1);
        float v = inter/(ai + aj - inter + 1e-9f);
        if (v > 0.5f) bits |= (1ull << jj);
      }
    }
  }
  iou[((size_t)b*NANCH + i)*32 + w] = bits;
}

// ---------------- greedy NMS scan ----------------
__global__ void nmsscan(const unsigned long long* __restrict__ iou,
                        const int* __restrict__ order, int* __restrict__ keep){
  const int b = blockIdx.x, lane = threadIdx.x;
  unsigned long long sup = 0ull;
  int k = 0;
  for (int i=0; i<NANCH && k<TOPK_N; i++){
    int wi = i >> 6, bi = i & 63;
    unsigned long long wv = __shfl(sup, wi);
    if (!((wv >> bi) & 1ull)){
      if (lane == 0) keep[b*TOPK_N + k] = order[(size_t)b*NANCH + i];
      k++;
      unsigned long long row = (lane < 32) ? iou[((size_t)b*NANCH + i)*32 + lane] : 0ull;
      sup |= row;
    }
  }
  for (int r = lane; r < TOPK_N; r += 64)
    if (r >= k) keep[b*TOPK_N + r] = -1;
}

// ---------------- gather kept results ----------------
__global__ void gatherk(const int* __restrict__ keep, const float* __restrict__ boxes,
                        const float* __restrict__ scores, const int* __restrict__ labels,
                        float* __restrict__ out){
  const int b = blockIdx.x, r = threadIdx.x;
  if (r >= TOPK_N) return;
  int ki = keep[b*TOPK_N + r];
  float valid = (ki >= 0) ? 1.f : 0.f;
  int kc = (ki < 0) ? 0 : ki;
  const float* bo = boxes + ((size_t)b*NANCH + kc)*4;
#pragma unroll
  for (int c=0;c<4;c++) out[OUT_BOXES + ((size_t)b*TOPK_N + r)*4 + c] = bo[c]*valid;
  out[OUT_SCORES + b*TOPK_N + r] = scores[(size_t)b*NANCH + kc]*valid;
  out[OUT_LABELS + b*TOPK_N + r] = (ki >= 0) ? (float)labels[(size_t)b*NANCH + kc] : 0.f;
  out[OUT_VALID  + b*TOPK_N + r] = valid;
}

// ---------------- mask logits + sigmoid ----------------
__global__ void maskm(const int* __restrict__ keep, const float* __restrict__ hout,
                      const float* __restrict__ proto, float* __restrict__ m){
  const int b = blockIdx.z, r = blockIdx.y;
  const int s = blockIdx.x*blockDim.x + threadIdx.x;
  __shared__ float cf[32];
  int ki = keep[b*TOPK_N + r];
  int kc = (ki < 0) ? 0 : ki;
  if (threadIdx.x < 32)
    cf[threadIdx.x] = hout[((size_t)b*64 + 25 + threadIdx.x)*NANCH + kc];
  __syncthreads();
  float acc = 0.f;
#pragma unroll
  for (int p=0;p<32;p++) acc = fmaf(cf[p], proto[((size_t)b*32 + p)*NANCH + s], acc);
  m[((size_t)b*TOPK_N + r)*NANCH + s] = 1.f/(1.f + expf(-acc));
}

// ---------------- bilinear 32x64 -> 256x512, threshold ----------------
__global__ void resizek(const float* __restrict__ m, const int* __restrict__ keep,
                        float* __restrict__ out){
  const int b = blockIdx.z, r = blockIdx.y;
  const int pid = blockIdx.x*blockDim.x + threadIdx.x;
  const int y  = pid >> 7;
  const int x4 = (pid & 127) << 2;
  bool valid = keep[b*TOPK_N + r] >= 0;
  const float* mb = m + ((size_t)b*TOPK_N + r)*NANCH;
  float sy = (y + 0.5f)*0.125f - 0.5f;
  sy = fminf(fmaxf(sy, 0.f), 31.f);
  int y0 = (int)floorf(sy);
  int y1 = min(y0+1, 31);
  float wy = sy - (float)y0;
  const float* r0 = mb + y0*64;
  const float* r1 = mb + y1*64;
  float res[4];
#pragma unroll
  for (int k=0;k<4;k++){
    int x = x4 + k;
    float sx = (x + 0.5f)*0.125f - 0.5f;
    sx = fminf(fmaxf(sx, 0.f), 63.f);
    int x0 = (int)floorf(sx);
    int x1 = min(x0+1, 63);
    float wx = sx - (float)x0;
    float t0 = r0[x0]*(1.f-wy) + r1[x0]*wy;
    float t1 = r0[x1]*(1.f-wy) + r1[x1]*wy;
    float v  = t0*(1.f-wx) + t1*wx;
    res[k] = (v > 0.5f && valid) ? 1.f : 0.f;
  }
  float4 v4 = make_float4(res[0], res[1], res[2], res[3]);
  *(float4*)(out + OUT_MASKS + (((size_t)b*TOPK_N + r)*256 + y)*512 + x4) = v4;
}

extern "C" void kernel_launch(void* const* d_in, const int* in_sizes, int n_in,
                              void* d_out, int out_size, void* d_ws, size_t ws_size,
                              hipStream_t stream) {
  const float* images=(const float*)d_in[0];
  const float* w1=(const float*)d_in[1];  const float* b1=(const float*)d_in[2];
  const float* w2=(const float*)d_in[3];  const float* b2=(const float*)d_in[4];
  const float* w3=(const float*)d_in[5];  const float* b3=(const float*)d_in[6];
  const float* pw1=(const float*)d_in[7]; const float* pb1=(const float*)d_in[8];
  const float* pw2=(const float*)d_in[9]; const float* pb2=(const float*)d_in[10];
  const float* cw=(const float*)d_in[11]; const float* cb=(const float*)d_in[12];
  const float* bw=(const float*)d_in[13]; const float* bb=(const float*)d_in[14];
  const float* kw=(const float*)d_in[15]; const float* kb=(const float*)d_in[16];
  float* out = (float*)d_out;
  char* ws = (char*)d_ws;

  short* x1hi = (short*)(ws + OFF_X1HI);
  short* x1lo = (short*)(ws + OFF_X1LO);
  short* x2hi = (short*)(ws + OFF_X2HI);
  short* x2lo = (short*)(ws + OFF_X2LO);
  short* fthi = (short*)(ws + OFF_FTHI);
  short* ftlo = (short*)(ws + OFF_FTLO);
  float* wT1  = (float*)(ws + OFF_WT1);
  short* a2h  = (short*)(ws + OFF_A2H);
  short* a2l  = (short*)(ws + OFF_A2L);
  short* a3h  = (short*)(ws + OFF_A3H);
  short* a3l  = (short*)(ws + OFF_A3L);
  short* ahh  = (short*)(ws + OFF_AHH);
  short* ahl  = (short*)(ws + OFF_AHL);
  short* ap1h = (short*)(ws + OFF_AP1H);
  short* ap1l = (short*)(ws + OFF_AP1L);
  float* wTp2 = (float*)(ws + OFF_WTP2);
  float* bh   = (float*)(ws + OFF_BH);
  float* hout = (float*)(ws + OFF_HOUT);
  float* p1   = (float*)(ws + OFF_P1);
  float* proto= (float*)(ws + OFF_PROTO);
  float* boxes= (float*)(ws + OFF_BOXES);
  float* scores=(float*)(ws + OFF_SCORES);
  int*   labels=(int*)  (ws + OFF_LABELS);
  int*   order =(int*)  (ws + OFF_ORDER);
  float* sb   = (float*)(ws + OFF_SB);
  unsigned long long* iou = (unsigned long long*)(ws + OFF_IOU);
  int*   keep = (int*)  (ws + OFF_KEEP);
  unsigned* maxb = (unsigned*)(ws + OFF_MAXB);
  float* m    = (float*)(ws + OFF_M);

  // zero activation planes + maxb (halos must be 0; harness poisons ws with 0xAA)
  zerok<<<dim3((unsigned)(ZERO_BYTES/16/256)), 256, 0, stream>>>((float4*)ws, (long)(ZERO_BYTES/16), maxb);

  // weight packing
  packw<3,64,9>  <<<dim3(7),    256, 0, stream>>>(w1, wT1);
  packA<64,128>  <<<dim3(288),  256, 0, stream>>>(w2, a2h, a2l);
  packA<128,256> <<<dim3(1152), 256, 0, stream>>>(w3, a3h, a3l);
  packA<256,256> <<<dim3(2304), 256, 0, stream>>>(pw1, ap1h, ap1l);
  packAh<<<dim3(576), 256, 0, stream>>>(cw, bw, kw, cb, bb, kb, ahh, ahl, bh);
  packw<256,32,1><<<dim3(32),   256, 0, stream>>>(pw2, wTp2);

  // conv1: direct fp32 -> x1 C8HW8 padded hi/lo
  conv1k<<<dim3(64,4,BB), 256, 0, stream>>>(images, wT1, b1, x1hi, x1lo);

  // conv2: split-bf16 implicit GEMM, global-direct B (R9-exact)
  cgemm<64,576,128,2,4,128,64,2,130,258,true,0,66,130>
      <<<dim3(128,1,BB), 256, 0, stream>>>(a2h, a2l, x1hi, x1lo, b2, nullptr, x2hi, x2lo);

  // conv3: split-bf16, hi-B LDS-staged rows (bit-exact R9 order), S=2
  cgemm_row<128,1152,256,2,4,2,66,130,true,0,34,66>
      <<<dim3(32,2,BB), 256, 0, stream>>>(a3h, a3l, x2hi, x2lo, b3, nullptr, fthi, ftlo);

  // heads: split-bf16, hi-B LDS-staged rows, S=1
  cgemm_row<256,2304,64,2,2,1,34,66,true,1,1,1>
      <<<dim3(32,1,BB), 128, 0, stream>>>(ahh, ahl, fthi, ftlo, bh, hout, nullptr, nullptr);

  // pw1 (mask path): plain bf16, hi-B LDS-staged rows, S=1
  cgemm_row<256,2304,256,2,4,1,34,66,false,2,1,1>
      <<<dim3(32,2,BB), 256, 0, stream>>>(ap1h, ap1l, fthi, fthi, pb1, p1, nullptr, nullptr);

  pw2k2<<<dim3(8,BB), 256, 0, stream>>>(p1, wTp2, pb2, proto);

  // decode + NMS (R9-exact chain)
  decodek<<<dim3(8,BB), 256, 0, stream>>>(hout, boxes, scores, labels, maxb);
  sortk<<<dim3(BB), 1024, 0, stream>>>(scores, boxes, labels, maxb, order, sb);
  ioumask<<<dim3(256,BB), 256, 0, stream>>>(sb, iou);
  nmsscan<<<dim3(BB), 64, 0, stream>>>(iou, order, keep);
  gatherk<<<dim3(BB), 128, 0, stream>>>(keep, boxes, scores, labels, out);

  // masks
  maskm<<<dim3(8,TOPK_N,BB), 256, 0, stream>>>(keep, hout, proto, m);
  resizek<<<dim3(128,TOPK_N,BB), 256, 0, stream>>>(m, keep, out);
}